// Round 4
// baseline (76.693 us; speedup 1.0000x reference)
//
#include <hip/hip_runtime.h>
#include <math.h>

#define CDIM   862
#define NRANK  8
#define KW     7
#define ROWS_PER_BLOCK 4
#define THREADS (ROWS_PER_BLOCK * 64)
#define SROW   872           // LDS row stride (floats): 4 left pad + 862 + pad, float2-aligned
#define LN_EPS 1e-5f

// One wave (64 lanes) owns one row of C=862. No cross-wave communication:
// stats reduce via in-wave shuffle butterfly; pre-norm y is written/read by
// the SAME lane in LDS. Single __syncthreads() covers the cross-lane x stage.
__global__ __launch_bounds__(THREADS) void cvmc_kernel(
    const float* __restrict__ x,
    const float* __restrict__ Wup,
    const float* __restrict__ bup,
    const float* __restrict__ Wdown,
    const float* __restrict__ bdown,
    const float* __restrict__ gamma,
    const float* __restrict__ beta,
    float* __restrict__ out,
    int nrows)
{
    const int lane = threadIdx.x & 63;
    const int wv   = threadIdx.x >> 6;
    const int row  = blockIdx.x * ROWS_PER_BLOCK + wv;

    __shared__ float sx[ROWS_PER_BLOCK][SROW];   // staged x with halo: sx[.][4+i] = x[i]
    __shared__ float sy[ROWS_PER_BLOCK][CDIM];   // pre-norm y (same-lane write->read)

    // Uniform weights -> scalar (SGPR) loads.
    float wu[NRANK][KW];
    float bu[NRANK], wd[NRANK];
#pragma unroll
    for (int r = 0; r < NRANK; ++r) {
#pragma unroll
        for (int k = 0; k < KW; ++k) wu[r][k] = Wup[r * KW + k];
        bu[r] = bup[r];
        wd[r] = Wdown[r];    // Wdown shape (1, RANK, 1) -> flat [r]
    }
    const float bd = bdown[0];

    const bool live = (row < nrows);
    float* s = sx[wv];
    float* yrow = sy[wv];

    if (live) {
        const float* __restrict__ xr = x + (size_t)row * CDIM;
        // Stage row, float2-coalesced (row base 8B-aligned: CDIM even).
        for (int i = lane; i < CDIM / 2; i += 64) {
            float2 v = reinterpret_cast<const float2*>(xr)[i];
            *reinterpret_cast<float2*>(&s[4 + 2 * i]) = v;
        }
        if (lane < 3) {
            s[1 + lane] = 0.0f;          // x[-3..-1]
            s[4 + CDIM + lane] = 0.0f;   // x[862..864]
        }
    }
    __syncthreads();

    float sum = 0.0f, sumsq = 0.0f;
    if (live) {
        // c = lane + 64*j ; window x[c-3..c+3] == s[c+1 .. c+7]
        for (int c = lane; c < CDIM; c += 64) {
            const float w0 = s[c + 1];
            const float w1 = s[c + 2];
            const float w2 = s[c + 3];
            const float w3 = s[c + 4];   // == x[c]
            const float w4 = s[c + 5];
            const float w5 = s[c + 6];
            const float w6 = s[c + 7];

            float acc = bd;
#pragma unroll
            for (int r = 0; r < NRANK; ++r) {
                float t = bu[r];
                t = fmaf(wu[r][0], w0, t);
                t = fmaf(wu[r][1], w1, t);
                t = fmaf(wu[r][2], w2, t);
                t = fmaf(wu[r][3], w3, t);
                t = fmaf(wu[r][4], w4, t);
                t = fmaf(wu[r][5], w5, t);
                t = fmaf(wu[r][6], w6, t);
                // exact GELU: 0.5*t*(1+erf(t/sqrt(2)))
                const float g = 0.5f * t * (1.0f + erff(t * 0.70710678118654752f));
                acc = fmaf(wd[r], g, acc);
            }
            const float y = w3 + acc;    // residual
            yrow[c] = y;                 // same lane rereads this below
            sum += y;
            sumsq = fmaf(y, y, sumsq);
        }
    }

    // In-wave butterfly: every lane ends with the row totals. No LDS, no barrier.
#pragma unroll
    for (int off = 1; off < 64; off <<= 1) {
        sum   += __shfl_xor(sum, off, 64);
        sumsq += __shfl_xor(sumsq, off, 64);
    }

    if (live) {
        const float inv  = 1.0f / (float)CDIM;
        const float mu   = sum * inv;
        const float var  = fmaf(sumsq, inv, -mu * mu);
        const float rstd = rsqrtf(var + LN_EPS);

        float* __restrict__ yr = out + (size_t)row * CDIM;
        for (int c = lane; c < CDIM; c += 64) {
            yr[c] = (yrow[c] - mu) * rstd * gamma[c] + beta[c];
        }
    }
}

extern "C" void kernel_launch(void* const* d_in, const int* in_sizes, int n_in,
                              void* d_out, int out_size, void* d_ws, size_t ws_size,
                              hipStream_t stream) {
    const float* x     = (const float*)d_in[0];
    const float* Wup   = (const float*)d_in[1];
    const float* bup   = (const float*)d_in[2];
    const float* Wdown = (const float*)d_in[3];
    const float* bdown = (const float*)d_in[4];
    const float* gamma = (const float*)d_in[5];
    const float* beta  = (const float*)d_in[6];
    float* out = (float*)d_out;

    const int nrows  = out_size / CDIM;                                // B*L = 11520
    const int nblk   = (nrows + ROWS_PER_BLOCK - 1) / ROWS_PER_BLOCK;  // 2880
    cvmc_kernel<<<nblk, THREADS, 0, stream>>>(x, Wup, bup, Wdown, bdown,
                                              gamma, beta, out, nrows);
}

// Round 5
// 54.479 us; speedup vs baseline: 1.4077x; 1.4077x over previous
//
#include <hip/hip_runtime.h>
#include <math.h>

#define CDIM   862
#define NRANK  8
#define KW     7
#define ROWS_PER_BLOCK 4
#define THREADS (ROWS_PER_BLOCK * 64)
#define SROW   872           // LDS row stride (floats): 4 left pad + 862 + pad, float2-aligned
#define LN_EPS 1e-5f
#define NJFULL 13            // 13*64 = 832 full slices
#define TAIL   (CDIM - NJFULL * 64)   // 30 lanes in the last slice

// One wave (64 lanes) owns one row of C=862. Stats reduce via in-wave
// shuffle butterfly; pre-norm y lives in registers (static-index unroll).
// GELU: tanh-form approximation, t*sigmoid(1.59577 t + 0.0713548 t^3),
// using v_exp_f32 + v_rcp_f32 (~8 ops vs ~50 for libm erff).
__global__ __launch_bounds__(THREADS) void cvmc_kernel(
    const float* __restrict__ x,
    const float* __restrict__ Wup,
    const float* __restrict__ bup,
    const float* __restrict__ Wdown,
    const float* __restrict__ bdown,
    const float* __restrict__ gamma,
    const float* __restrict__ beta,
    float* __restrict__ out,
    int nrows)
{
    const int lane = threadIdx.x & 63;
    const int wv   = threadIdx.x >> 6;
    const int row  = blockIdx.x * ROWS_PER_BLOCK + wv;

    __shared__ float sx[ROWS_PER_BLOCK][SROW];   // staged x with halo: sx[.][4+i] = x[i]

    // Uniform weights -> scalar (SGPR) loads.
    float wu[NRANK][KW];
    float bu[NRANK], wd[NRANK];
#pragma unroll
    for (int r = 0; r < NRANK; ++r) {
#pragma unroll
        for (int k = 0; k < KW; ++k) wu[r][k] = Wup[r * KW + k];
        bu[r] = bup[r];
        wd[r] = Wdown[r];    // Wdown shape (1, RANK, 1) -> flat [r]
    }
    const float bd = bdown[0];

    const bool live = (row < nrows);
    float* s = sx[wv];

    if (live) {
        const float* __restrict__ xr = x + (size_t)row * CDIM;
        // Stage row, float2-coalesced (row base 8B-aligned: CDIM even).
        for (int i = lane; i < CDIM / 2; i += 64) {
            float2 v = reinterpret_cast<const float2*>(xr)[i];
            *reinterpret_cast<float2*>(&s[4 + 2 * i]) = v;
        }
        if (lane < 3) {
            s[1 + lane] = 0.0f;          // x[-3..-1]
            s[4 + CDIM + lane] = 0.0f;   // x[862..864]
        }
    }
    __syncthreads();

    // conv -> tanh-GELU -> down-proj -> residual for element c.
    auto compute = [&](int c) -> float {
        const float w0 = s[c + 1];
        const float w1 = s[c + 2];
        const float w2 = s[c + 3];
        const float w3 = s[c + 4];   // == x[c]
        const float w4 = s[c + 5];
        const float w5 = s[c + 6];
        const float w6 = s[c + 7];

        float acc = bd;
#pragma unroll
        for (int r = 0; r < NRANK; ++r) {
            float t = bu[r];
            t = fmaf(wu[r][0], w0, t);
            t = fmaf(wu[r][1], w1, t);
            t = fmaf(wu[r][2], w2, t);
            t = fmaf(wu[r][3], w3, t);
            t = fmaf(wu[r][4], w4, t);
            t = fmaf(wu[r][5], w5, t);
            t = fmaf(wu[r][6], w6, t);
            // gelu(t) ~= t * sigmoid(1.5957691*t + 0.07135482*t^3)
            const float t2 = t * t;
            const float z  = t * fmaf(t2, -0.0713548162f, -1.5957691216f);
            const float e  = __expf(z);                       // v_mul + v_exp_f32
            const float g  = t * __builtin_amdgcn_rcpf(1.0f + e);
            acc = fmaf(wd[r], g, acc);
        }
        return w3 + acc;   // residual
    };

    float yv[NJFULL + 1];
    float sum = 0.0f, sumsq = 0.0f;
    if (live) {
#pragma unroll
        for (int j = 0; j < NJFULL; ++j) {           // static indices only (no scratch)
            const float y = compute(lane + 64 * j);
            yv[j] = y;
            sum += y;
            sumsq = fmaf(y, y, sumsq);
        }
        if (lane < TAIL) {
            const float y = compute(lane + 64 * NJFULL);
            yv[NJFULL] = y;
            sum += y;
            sumsq = fmaf(y, y, sumsq);
        }
    }

    // In-wave butterfly: every lane ends with the row totals.
#pragma unroll
    for (int off = 1; off < 64; off <<= 1) {
        sum   += __shfl_xor(sum, off, 64);
        sumsq += __shfl_xor(sumsq, off, 64);
    }

    if (live) {
        const float inv  = 1.0f / (float)CDIM;
        const float mu   = sum * inv;
        const float var  = fmaf(sumsq, inv, -mu * mu);
        const float rstd = rsqrtf(var + LN_EPS);

        float* __restrict__ yr = out + (size_t)row * CDIM;
#pragma unroll
        for (int j = 0; j < NJFULL; ++j) {
            const int c = lane + 64 * j;
            yr[c] = (yv[j] - mu) * rstd * gamma[c] + beta[c];
        }
        if (lane < TAIL) {
            const int c = lane + 64 * NJFULL;
            yr[c] = (yv[NJFULL] - mu) * rstd * gamma[c] + beta[c];
        }
    }
}

extern "C" void kernel_launch(void* const* d_in, const int* in_sizes, int n_in,
                              void* d_out, int out_size, void* d_ws, size_t ws_size,
                              hipStream_t stream) {
    const float* x     = (const float*)d_in[0];
    const float* Wup   = (const float*)d_in[1];
    const float* bup   = (const float*)d_in[2];
    const float* Wdown = (const float*)d_in[3];
    const float* bdown = (const float*)d_in[4];
    const float* gamma = (const float*)d_in[5];
    const float* beta  = (const float*)d_in[6];
    float* out = (float*)d_out;

    const int nrows  = out_size / CDIM;                                // B*L = 11520
    const int nblk   = (nrows + ROWS_PER_BLOCK - 1) / ROWS_PER_BLOCK;  // 2880
    cvmc_kernel<<<nblk, THREADS, 0, stream>>>(x, Wup, bup, Wdown, bdown,
                                              gamma, beta, out, nrows);
}

// Round 6
// 47.767 us; speedup vs baseline: 1.6055x; 1.1405x over previous
//
#include <hip/hip_runtime.h>
#include <math.h>

#define CDIM   862
#define NPAIR  (CDIM / 2)            // 431 float2 pairs per row
#define NRANK  8
#define KW     7
#define ROWS_PER_BLOCK 4
#define THREADS (ROWS_PER_BLOCK * 64)
#define SROW   872                   // 4 left-pad + 862 + 4 right-pad = 870 -> 872 (8B align)
#define LN_EPS 1e-5f
#define NJ     7                     // 6 full pair-slices + tail
#define TAILP  (NPAIR - 6 * 64)      // 47 pairs in the tail slice

// One wave owns one row. Each lane owns element-pairs (2m, 2m+1), m = lane+64j.
// Window x[2m-4 .. 2m+5] read as 5x ds_read_b64; next slice's window is
// prefetched (double-buffered, statically unrolled) while current computes.
// GELU via tanh-sigmoid with rank-paired rcp: one v_rcp per 2 ranks.
__global__ __launch_bounds__(THREADS) void cvmc_kernel(
    const float* __restrict__ x,
    const float* __restrict__ Wup,
    const float* __restrict__ bup,
    const float* __restrict__ Wdown,
    const float* __restrict__ bdown,
    const float* __restrict__ gamma,
    const float* __restrict__ beta,
    float* __restrict__ out,
    int nrows)
{
    const int lane = threadIdx.x & 63;
    const int wv   = threadIdx.x >> 6;
    const int row  = blockIdx.x * ROWS_PER_BLOCK + wv;

    __shared__ float sx[ROWS_PER_BLOCK][SROW];   // sx[.][4+i] = x[i]

    // Uniform weights -> SGPR scalar loads.
    float wu[NRANK][KW];
    float bu[NRANK], wd[NRANK];
#pragma unroll
    for (int r = 0; r < NRANK; ++r) {
#pragma unroll
        for (int k = 0; k < KW; ++k) wu[r][k] = Wup[r * KW + k];
        bu[r] = bup[r];
        wd[r] = Wdown[r];
    }
    const float bd = bdown[0];

    const bool live = (row < nrows);
    float* s = sx[wv];

    if (live) {
        const float* __restrict__ xr = x + (size_t)row * CDIM;
        for (int i = lane; i < NPAIR; i += 64) {
            float2 v = reinterpret_cast<const float2*>(xr)[i];
            *reinterpret_cast<float2*>(&s[4 + 2 * i]) = v;
        }
        if (lane < 4) {
            s[lane] = 0.0f;              // x[-4..-1]
            s[4 + CDIM + lane] = 0.0f;   // x[862..865]
        }
    }
    __syncthreads();

    const float2* sp = reinterpret_cast<const float2*>(s);  // float2 idx m = floats s[2m],s[2m+1]

    const float C1 = -0.0713548162f;   // gelu(t) ~ t*sigmoid(1.5957691 t + 0.07135482 t^3)
    const float C0 = -1.5957691216f;

    float2 yv[NJ];
    float sum = 0.0f, sumsq = 0.0f;

    float2 wbuf[2][5];
    if (live) {
#pragma unroll
        for (int q = 0; q < 5; ++q) wbuf[0][q] = sp[lane + q];   // prologue: slice 0 window
    }

    if (live) {
#pragma unroll
        for (int j = 0; j < NJ; ++j) {
            const int cur = j & 1;
            const int nxt = cur ^ 1;
            // Prefetch next slice's window (double buffer; all indices static after unroll).
            if (j + 1 < NJ) {
                if ((j + 1 < NJ - 1) || (lane < TAILP)) {
                    const int mn = lane + 64 * (j + 1);
#pragma unroll
                    for (int q = 0; q < 5; ++q) wbuf[nxt][q] = sp[mn + q];
                }
            }
            if ((j < NJ - 1) || (lane < TAILP)) {
                // w[i] = x[2m-4+i]; elem0 (c=2m) uses w[1..7], elem1 uses w[2..8].
                float w[10];
#pragma unroll
                for (int q = 0; q < 5; ++q) {
                    w[2 * q]     = wbuf[cur][q].x;
                    w[2 * q + 1] = wbuf[cur][q].y;
                }
                float acc0 = bd, acc1 = bd;
#pragma unroll
                for (int rp = 0; rp < NRANK / 2; ++rp) {
                    const int ra = 2 * rp, rb = 2 * rp + 1;
                    float ta0 = bu[ra], ta1 = bu[ra];
                    float tb0 = bu[rb], tb1 = bu[rb];
#pragma unroll
                    for (int k = 0; k < KW; ++k) {
                        ta0 = fmaf(wu[ra][k], w[k + 1], ta0);
                        ta1 = fmaf(wu[ra][k], w[k + 2], ta1);
                        tb0 = fmaf(wu[rb][k], w[k + 1], tb0);
                        tb1 = fmaf(wu[rb][k], w[k + 2], tb1);
                    }
                    // z = t * (C0 + C1*t^2) ; e = exp(z) ; u = 1+e
                    const float za0 = ta0 * fmaf(ta0 * ta0, C1, C0);
                    const float za1 = ta1 * fmaf(ta1 * ta1, C1, C0);
                    const float zb0 = tb0 * fmaf(tb0 * tb0, C1, C0);
                    const float zb1 = tb1 * fmaf(tb1 * tb1, C1, C0);
                    const float ua0 = 1.0f + __expf(za0);
                    const float ua1 = 1.0f + __expf(za1);
                    const float ub0 = 1.0f + __expf(zb0);
                    const float ub1 = 1.0f + __expf(zb1);
                    // wd_a*t_a/u_a + wd_b*t_b/u_b = (a_a*u_b + a_b*u_a) / (u_a*u_b)
                    const float r0 = __builtin_amdgcn_rcpf(ua0 * ub0);
                    const float r1 = __builtin_amdgcn_rcpf(ua1 * ub1);
                    const float aa0 = wd[ra] * ta0, aa1 = wd[ra] * ta1;
                    const float ab0 = wd[rb] * tb0, ab1 = wd[rb] * tb1;
                    float n0 = aa0 * ub0; n0 = fmaf(ab0, ua0, n0);
                    float n1 = aa1 * ub1; n1 = fmaf(ab1, ua1, n1);
                    acc0 = fmaf(n0, r0, acc0);
                    acc1 = fmaf(n1, r1, acc1);
                }
                const float y0 = w[4] + acc0;   // x[2m]   + h
                const float y1 = w[5] + acc1;   // x[2m+1] + h
                yv[j] = make_float2(y0, y1);
                sum += y0 + y1;
                sumsq = fmaf(y0, y0, sumsq);
                sumsq = fmaf(y1, y1, sumsq);
            }
        }
    }

    // In-wave butterfly: every lane ends with row totals. No LDS, no barrier.
#pragma unroll
    for (int off = 1; off < 64; off <<= 1) {
        sum   += __shfl_xor(sum, off, 64);
        sumsq += __shfl_xor(sumsq, off, 64);
    }

    if (live) {
        const float inv  = 1.0f / (float)CDIM;
        const float mu   = sum * inv;
        const float var  = fmaf(sumsq, inv, -mu * mu);
        const float rstd = rsqrtf(var + LN_EPS);

        float2* __restrict__ yr2 = reinterpret_cast<float2*>(out + (size_t)row * CDIM);
        const float2* g2 = reinterpret_cast<const float2*>(gamma);
        const float2* b2 = reinterpret_cast<const float2*>(beta);
#pragma unroll
        for (int j = 0; j < NJ; ++j) {
            if ((j < NJ - 1) || (lane < TAILP)) {
                const int m = lane + 64 * j;
                const float2 gv = g2[m];
                const float2 bv = b2[m];
                float2 o;
                o.x = fmaf((yv[j].x - mu) * rstd, gv.x, bv.x);
                o.y = fmaf((yv[j].y - mu) * rstd, gv.y, bv.y);
                yr2[m] = o;
            }
        }
    }
}

extern "C" void kernel_launch(void* const* d_in, const int* in_sizes, int n_in,
                              void* d_out, int out_size, void* d_ws, size_t ws_size,
                              hipStream_t stream) {
    const float* x     = (const float*)d_in[0];
    const float* Wup   = (const float*)d_in[1];
    const float* bup   = (const float*)d_in[2];
    const float* Wdown = (const float*)d_in[3];
    const float* bdown = (const float*)d_in[4];
    const float* gamma = (const float*)d_in[5];
    const float* beta  = (const float*)d_in[6];
    float* out = (float*)d_out;

    const int nrows = out_size / CDIM;                                 // 11520
    const int nblk  = (nrows + ROWS_PER_BLOCK - 1) / ROWS_PER_BLOCK;   // 2880
    cvmc_kernel<<<nblk, THREADS, 0, stream>>>(x, Wup, bup, Wdown, bdown,
                                              gamma, beta, out, nrows);
}